// Round 1
// 1950.351 us; speedup vs baseline: 1.1972x; 1.1972x over previous
//
#include <hip/hip_runtime.h>

// SimpleRNN: B=64,T=512,I=128,H=1024,L=4,O=128
// Round 5: round-4 skeleton + software-pipelined input projection (a3 for
// step t+1 computed in the publish->observe dead window), deferred s3 scatter
// stores off the publish path, and split dependent MFMA accumulation chains.
#define B_ 64
#define T_ 512
#define I_ 128
#define H_ 1024
#define L_ 4
#define O_ 128
#define M_ (B_ * T_)
#define D_ 32  // inter-layer seq ring depth (steps)

typedef __attribute__((ext_vector_type(8))) short bf16x8_t;
typedef __attribute__((ext_vector_type(4))) float f32x4_t;

__device__ __forceinline__ unsigned short f2bf(float x) {
  unsigned int u = __builtin_bit_cast(unsigned int, x);
  u += 0x7FFFu + ((u >> 16) & 1u);
  return (unsigned short)(u >> 16);
}
__device__ __forceinline__ float bf2f(unsigned short h) {
  return __builtin_bit_cast(float, ((unsigned int)h) << 16);
}
__device__ __forceinline__ f32x4_t mfma16(bf16x8_t a, bf16x8_t b, f32x4_t c) {
  return __builtin_amdgcn_mfma_f32_16x16x32_bf16(a, b, c, 0, 0, 0);
}

// Relaxed agent-scope atomics (served at device coherence point; proven r2).
__device__ __forceinline__ unsigned aldc(const unsigned* p) {
  return __hip_atomic_load(p, __ATOMIC_RELAXED, __HIP_MEMORY_SCOPE_AGENT);
}
__device__ __forceinline__ unsigned long long ald64(const unsigned long long* p) {
  return __hip_atomic_load(p, __ATOMIC_RELAXED, __HIP_MEMORY_SCOPE_AGENT);
}
__device__ __forceinline__ void ast32(unsigned* p, unsigned v) {
  __hip_atomic_store(p, v, __ATOMIC_RELAXED, __HIP_MEMORY_SCOPE_AGENT);
}

// All 256 threads: poll 16 member counters (stride 32 u32 = 128B lines) until
// all >= target; returns the group min (uniform per 16-lane subgroup).
__device__ __forceinline__ unsigned wait_ge(const unsigned* base, unsigned target) {
  const int i = threadIdx.x & 15;
  unsigned v;
  while (true) {
    v = aldc(base + i * 32);
    if (__ballot(v < target) == 0ull) break;
    __builtin_amdgcn_s_sleep(2);
  }
  unsigned mn = v;
  mn = min(mn, (unsigned)__shfl_xor((int)mn, 1));
  mn = min(mn, (unsigned)__shfl_xor((int)mn, 2));
  mn = min(mn, (unsigned)__shfl_xor((int)mn, 4));
  mn = min(mn, (unsigned)__shfl_xor((int)mn, 8));
  return mn;
}

// Own-group barrier poll: no min-reduce needed (value never cached).
__device__ __forceinline__ void wait_all(const unsigned* base, unsigned target) {
  const int i = threadIdx.x & 15;
  while (true) {
    unsigned v = aldc(base + i * 32);
    if (__ballot(v < target) == 0ull) break;
    __builtin_amdgcn_s_sleep(2);
  }
}

// ---------------------------------------------------------------------------
// MFMA GEMM (round-1, proven) — used only for the final FC here.
// ---------------------------------------------------------------------------
template <int K, int N, bool ASPLIT, bool OUTBF16>
__global__ __launch_bounds__(256, 2) void gemm_k(
    const void* __restrict__ Aq, const float* __restrict__ Wf,
    const float* __restrict__ bias1, const float* __restrict__ bias2,
    void* __restrict__ Cq) {
  extern __shared__ unsigned short smem[];
  unsigned short* Ahi = smem;
  unsigned short* Alo = Ahi + (ASPLIT ? 8192 : 0);
  unsigned short* Bhi = Alo + 8192;
  unsigned short* Blo = Bhi + 8192;

  const int tid = threadIdx.x;
  const int wave = tid >> 6, lane = tid & 63;
  const int wm = wave >> 1, wn = wave & 1;
  const int lm = lane & 15, lk = lane >> 4;
  const int m0 = blockIdx.y * 128, n0 = blockIdx.x * 128;

  f32x4_t acc[4][4] = {};

  for (int kc = 0; kc < K; kc += 64) {
    __syncthreads();
#pragma unroll
    for (int p = 0; p < 4; ++p) {
      int fl = p * 256 + tid;
      int row = fl & 127, ko = (fl >> 7) & 3, kit = fl >> 9;
      int kk = kc + kit * 32 + ko * 8;
      if (ASPLIT) {
        const float* src = (const float*)Aq + (size_t)(m0 + row) * K + kk;
        union { bf16x8_t s; unsigned short u[8]; } th, tl;
#pragma unroll
        for (int e = 0; e < 8; ++e) {
          float v = src[e];
          unsigned short h = f2bf(v);
          th.u[e] = (short)h;
          tl.u[e] = (short)f2bf(v - bf2f(h));
        }
        *(bf16x8_t*)(Ahi + (size_t)fl * 8) = th.s;
        *(bf16x8_t*)(Alo + (size_t)fl * 8) = tl.s;
      } else {
        const unsigned short* src = (const unsigned short*)Aq + (size_t)(m0 + row) * K + kk;
        *(bf16x8_t*)(Ahi + (size_t)fl * 8) = *(const bf16x8_t*)src;
      }
    }
#pragma unroll
    for (int p = 0; p < 4; ++p) {
      int fl = p * 256 + tid;
      int row = fl & 127, ko = (fl >> 7) & 3, kit = fl >> 9;
      int kk = kc + kit * 32 + ko * 8;
      const float* src = Wf + (size_t)(n0 + row) * K + kk;
      union { bf16x8_t s; unsigned short u[8]; } th, tl;
#pragma unroll
      for (int e = 0; e < 8; ++e) {
        float v = src[e];
        unsigned short h = f2bf(v);
        th.u[e] = (short)h;
        tl.u[e] = (short)f2bf(v - bf2f(h));
      }
      *(bf16x8_t*)(Bhi + (size_t)fl * 8) = th.s;
      *(bf16x8_t*)(Blo + (size_t)fl * 8) = tl.s;
    }
    __syncthreads();
#pragma unroll
    for (int kit = 0; kit < 2; ++kit) {
      bf16x8_t bhf[4], blf[4];
#pragma unroll
      for (int n = 0; n < 4; ++n) {
        int br = wn * 64 + n * 16 + lm;
        bhf[n] = *(const bf16x8_t*)(Bhi + ((size_t)(kit * 4 + lk) * 128 + br) * 8);
        blf[n] = *(const bf16x8_t*)(Blo + ((size_t)(kit * 4 + lk) * 128 + br) * 8);
      }
#pragma unroll
      for (int m = 0; m < 4; ++m) {
        int ar = wm * 64 + m * 16 + lm;
        bf16x8_t a = *(const bf16x8_t*)(Ahi + ((size_t)(kit * 4 + lk) * 128 + ar) * 8);
        bf16x8_t al;
        if (ASPLIT) al = *(const bf16x8_t*)(Alo + ((size_t)(kit * 4 + lk) * 128 + ar) * 8);
#pragma unroll
        for (int n = 0; n < 4; ++n) {
          acc[m][n] = mfma16(a, bhf[n], acc[m][n]);
          acc[m][n] = mfma16(a, blf[n], acc[m][n]);
          if (ASPLIT) acc[m][n] = mfma16(al, bhf[n], acc[m][n]);
        }
      }
    }
  }
#pragma unroll
  for (int n = 0; n < 4; ++n) {
    int col = n0 + wn * 64 + n * 16 + lm;
    float bv = bias1[col];
    if (bias2 != nullptr) bv += bias2[col];
#pragma unroll
    for (int m = 0; m < 4; ++m) {
#pragma unroll
      for (int r = 0; r < 4; ++r) {
        int row = m0 + wm * 64 + m * 16 + lk * 4 + r;
        float v = acc[m][n][r] + bv;
        if (OUTBF16)
          ((unsigned short*)Cq)[(size_t)row * N + col] = f2bf(v);
        else
          ((float*)Cq)[(size_t)row * N + col] = v;
      }
    }
  }
}

// x pre-split: fp32 -> (hi, lo) bf16 planes.
__global__ __launch_bounds__(256) void splitx_k(const float* __restrict__ x,
                                               unsigned short* __restrict__ xhi,
                                               unsigned short* __restrict__ xlo) {
  int i = (blockIdx.x * 256 + threadIdx.x) * 4;
  float4 v = *(const float4*)(x + i);
  ushort4 h, lo;
  h.x = f2bf(v.x); lo.x = f2bf(v.x - bf2f(h.x));
  h.y = f2bf(v.y); lo.y = f2bf(v.y - bf2f(h.y));
  h.z = f2bf(v.z); lo.z = f2bf(v.z - bf2f(h.z));
  h.w = f2bf(v.w); lo.w = f2bf(v.w - bf2f(h.w));
  *(ushort4*)(xhi + i) = h;
  *(ushort4*)(xlo + i) = lo;
}

// ---------------------------------------------------------------------------
// Persistent pipelined RNN (round-2 geometry): 256 blocks, block = (l = bid>>6,
// me = (bid&63)>>2, bg = bid&3); 64 neurons x 16 batches per block; group
// (l,bg) = 16 member blocks. h ring bf16-hi only, [k/8][b][k%8] frag order.
// Progress: per-block counter (own 128B line), relaxed sc1 store of t+2 after
// step t (preceded by __syncthreads, which drains vmcnt -> release semantics);
// init stores 1. Polls: 16-wide ballot over member lines.
// Round-5 pipeline per step t:
//   dn-wait | own-wait(t) | h gather+stage | sync | a0 MFMA | epilogue(+a3s)
//   | sync | publish(t+2) | deferred s3 | [precompute a3s for t+1: up-wait,
//   seq gather+stage, sync, a3 MFMA]  <- hidden in publish->observe window
// ---------------------------------------------------------------------------
__global__ __launch_bounds__(256, 1) void rnn_k(
    const float* __restrict__ hidden,
    const float* __restrict__ Wih0, const float* __restrict__ Whh0,
    const float* __restrict__ bih0, const float* __restrict__ bhh0,
    const float* __restrict__ WihL, const float* __restrict__ WhhL,
    const float* __restrict__ bihL, const float* __restrict__ bhhL,
    const unsigned short* __restrict__ xhi, const unsigned short* __restrict__ xlo,
    unsigned short* __restrict__ ring, unsigned short* __restrict__ seqr,
    unsigned short* __restrict__ s3, float* __restrict__ hn,
    unsigned* __restrict__ prog) {
  extern __shared__ char lds[];  // 64 KB: h 32K | seq 32K
  char* ldsH = lds;
  char* ldsS = lds + 32768;
  const int tid = threadIdx.x;
  const int wave = tid >> 6, lane = tid & 63;
  const int lm = lane & 15, lk = lane >> 4;
  const int bid = blockIdx.x;
  const int l = bid >> 6;
  const int sub = bid & 63;
  const int me = sub >> 2, bg = sub & 3;
  const int g = l * 4 + bg;
  const int j0 = me * 64 + wave * 16;
  const int j = j0 + lm;

  // ---- weight fragments (bf16-hi) in registers
  const float* Whh = (l == 0) ? Whh0 : WhhL + (size_t)(l - 1) * H_ * H_;
  bf16x8_t bh[32];
#pragma unroll
  for (int kit = 0; kit < 32; ++kit) {
    const float* src = Whh + (size_t)j * H_ + kit * 32 + lk * 8;
    union { bf16x8_t s; unsigned short u[8]; } th;
#pragma unroll
    for (int e = 0; e < 8; ++e) th.u[e] = (short)f2bf(src[e]);
    bh[kit] = th.s;
  }
  bf16x8_t bw[32];
  bf16x8_t w0h[4], w0l[4];
  if (l > 0) {
    const float* Wih = WihL + (size_t)(l - 1) * H_ * H_;
#pragma unroll
    for (int kit = 0; kit < 32; ++kit) {
      const float* src = Wih + (size_t)j * H_ + kit * 32 + lk * 8;
      union { bf16x8_t s; unsigned short u[8]; } th;
#pragma unroll
      for (int e = 0; e < 8; ++e) th.u[e] = (short)f2bf(src[e]);
      bw[kit] = th.s;
    }
  } else {
#pragma unroll
    for (int kit = 0; kit < 4; ++kit) {
      const float* src = Wih0 + (size_t)j * I_ + kit * 32 + lk * 8;
      union { bf16x8_t s; unsigned short u[8]; } th, tl;
#pragma unroll
      for (int e = 0; e < 8; ++e) {
        float v = src[e];
        unsigned short h = f2bf(v);
        th.u[e] = (short)h;
        tl.u[e] = (short)f2bf(v - bf2f(h));
      }
      w0h[kit] = th.s; w0l[kit] = tl.s;
    }
  }
  float bias = (l == 0) ? (bih0[j] + bhh0[j])
                        : (bihL[(size_t)(l - 1) * H_ + j] + bhhL[(size_t)(l - 1) * H_ + j]);

  // ---- init: h0 -> ring slot 1 (this block's 64-neuron portion, u32-packed)
  {
    unsigned* r1 = (unsigned*)(ring + ((size_t)(l * 2 + 1) * 4 + bg) * 16384);
#pragma unroll
    for (int q = 0; q < 2; ++q) {
      int s = q * 256 + tid;  // [0,512) -> u32 idx me*512 + s
      int J = s >> 6, b16 = (s >> 2) & 15, h4 = s & 3;
      int jj = me * 64 + J * 8 + h4 * 2;
      const float* hp = hidden + (size_t)l * B_ * H_ + (bg * 16 + b16) * H_ + jj;
      unsigned p0 = f2bf(hp[0]), p1 = f2bf(hp[1]);
      ast32(r1 + me * 512 + s, p0 | (p1 << 16));
    }
  }
  __syncthreads();  // drains vmcnt for the whole block
  if (tid == 0) ast32(prog + (size_t)(g * 16 + me) * 32, 1u);

  const unsigned* ownB = prog + (size_t)g * 512;
  const unsigned* upB = prog + (size_t)((l - 1) * 4 + bg) * 512;  // l>0 only
  const unsigned* dnB = prog + (size_t)((l + 1) * 4 + bg) * 512;  // l<3 only
  unsigned upMin = 1, dnMin = 1;
  f32x4_t a3s = {0.f, 0.f, 0.f, 0.f};

  // ---- input-projection precompute for step tt (fills a3s).
  // For l>0: up-wait >= tt+2, gather seq slot, stage ldsS, sync, 32 MFMA
  // (2 independent chains). For l==0: direct x-fragment loads + 12 MFMA.
  auto precompute = [&](int tt) {
    if (l > 0) {
      if (upMin < (unsigned)(tt + 2)) upMin = wait_ge(upB, (unsigned)(tt + 2));
      asm volatile("" ::: "memory");
      unsigned long long stmp[16];
      const unsigned long long* sp = (const unsigned long long*)(seqr +
          ((size_t)((l - 1) * D_ + (tt & (D_ - 1))) * 4 + bg) * 16384);
#pragma unroll
      for (int i = 0; i < 16; ++i) stmp[i] = ald64(sp + i * 256 + tid);
      unsigned long long* dsp = (unsigned long long*)ldsS;
#pragma unroll
      for (int i = 0; i < 16; ++i) dsp[i * 256 + tid] = stmp[i];
      __syncthreads();
      f32x4_t xa = {0.f, 0.f, 0.f, 0.f}, xb = {0.f, 0.f, 0.f, 0.f};
#pragma unroll
      for (int kit = 0; kit < 32; ++kit) {
        const int fo = ((kit * 4 + lk) * 16 + lm) * 16;
        bf16x8_t as = *(const bf16x8_t*)(ldsS + fo);
        if (kit & 1) xb = mfma16(as, bw[kit], xb);
        else         xa = mfma16(as, bw[kit], xa);
      }
      a3s = xa + xb;
    } else {
      const int b = bg * 16 + lm;
      f32x4_t xa = {0.f, 0.f, 0.f, 0.f}, xb = {0.f, 0.f, 0.f, 0.f};
#pragma unroll
      for (int kit = 0; kit < 4; ++kit) {
        const size_t xo = ((size_t)b * T_ + tt) * I_ + kit * 32 + lk * 8;
        bf16x8_t xh = *(const bf16x8_t*)(xhi + xo);
        bf16x8_t xl = *(const bf16x8_t*)(xlo + xo);
        xa = mfma16(xh, w0h[kit], xa);
        xb = mfma16(xl, w0h[kit], xb);
        xa = mfma16(xh, w0l[kit], xa);
      }
      a3s = xa + xb;
    }
  };

  precompute(0);

  for (int t = 0; t < T_; ++t) {
    // A. downstream back-pressure before overwriting seq slot (cached)
    if (l < 3 && t >= D_) {
      if (dnMin < (unsigned)(t - D_ + 2)) dnMin = wait_ge(dnB, (unsigned)(t - D_ + 2));
    }
    // B. own-group barrier: peers finished step t-1 (h_{t-1} visible)
    wait_all(ownB, (unsigned)(t + 1));
    asm volatile("" ::: "memory");
    // C. h slice gather (32 KB bf16-hi) + stage to LDS (frag order preserved)
    unsigned long long htmp[16];
    const unsigned long long* hp = (const unsigned long long*)(ring +
        ((size_t)(l * 2 + ((t & 1) ^ 1)) * 4 + bg) * 16384);
#pragma unroll
    for (int i = 0; i < 16; ++i) htmp[i] = ald64(hp + i * 256 + tid);
    {
      unsigned long long* dh = (unsigned long long*)ldsH;
#pragma unroll
      for (int i = 0; i < 16; ++i) dh[i * 256 + tid] = htmp[i];
    }
    __syncthreads();
    // D. MFMA: a0 = h @ Whh^T (2 independent accumulation chains)
    f32x4_t h0a = {0.f, 0.f, 0.f, 0.f}, h0b = {0.f, 0.f, 0.f, 0.f};
#pragma unroll
    for (int kit = 0; kit < 32; ++kit) {
      const int fo = ((kit * 4 + lk) * 16 + lm) * 16;
      bf16x8_t ah = *(const bf16x8_t*)(ldsH + fo);
      if (kit & 1) h0b = mfma16(ah, bh[kit], h0b);
      else         h0a = mfma16(ah, bh[kit], h0a);
    }
    // E. epilogue: lane holds (j, b = bg*16 + lk*4 + r); u32 pair-packed stores
    unsigned* rwu = (unsigned*)(ring + ((size_t)(l * 2 + (t & 1)) * 4 + bg) * 16384);
    unsigned* swu = (unsigned*)(seqr + ((size_t)(l * D_ + (t & (D_ - 1))) * 4 + bg) * 16384);
    unsigned hi4[4];
#pragma unroll
    for (int r = 0; r < 4; ++r) {
      const int b15 = lk * 4 + r;
      float v = h0a[r] + h0b[r] + a3s[r] + bias;
      v = fmaxf(v, 0.f);
      unsigned hi = f2bf(v);
      hi4[r] = hi;
      unsigned other = (unsigned)__shfl_xor((int)hi, 1);
      if (!(lm & 1)) {
        const unsigned pk = hi | (other << 16);
        const int p32 = ((j >> 3) * 16 + b15) * 4 + ((j & 7) >> 1);
        ast32(rwu + p32, pk);
        if (l < 3) ast32(swu + p32, pk);
      }
      if (t == T_ - 1) hn[(size_t)l * B_ * H_ + (bg * 16 + b15) * H_ + j] = v;
    }
    // F. release: __syncthreads drains all waves' vmcnt, then publish progress
    __syncthreads();
    if (tid == 0) ast32(prog + (size_t)(g * 16 + me) * 32, (unsigned)(t + 2));
    // G. deferred scatter stores (not needed by peers; off the publish path)
    if (l == 3) {
#pragma unroll
      for (int r = 0; r < 4; ++r)
        s3[((size_t)(bg * 16 + lk * 4 + r) * T_ + t) * H_ + j] = (unsigned short)hi4[r];
    }
    // H. precompute a3s for step t+1 inside the publish->observe window
    if (t + 1 < T_) precompute(t + 1);
  }
}

// ---------------------------------------------------------------------------
// ws layout: prog 32KB (16 groups x 16 members x 128B) | pad to 64K |
// ring 1MB (u16 [l][slot2][bg][16384]) | seqr 12MB | s3 64MB | xhi 8MB |
// xlo 8MB  => ~93 MB.
// ---------------------------------------------------------------------------
extern "C" void kernel_launch(void* const* d_in, const int* in_sizes, int n_in,
                              void* d_out, int out_size, void* d_ws, size_t ws_size,
                              hipStream_t stream) {
  const float* x = (const float*)d_in[0];
  const float* hidden = (const float*)d_in[1];
  const float* Wih0 = (const float*)d_in[2];
  const float* Whh0 = (const float*)d_in[3];
  const float* bih0 = (const float*)d_in[4];
  const float* bhh0 = (const float*)d_in[5];
  const float* WihL = (const float*)d_in[6];
  const float* WhhL = (const float*)d_in[7];
  const float* bihL = (const float*)d_in[8];
  const float* bhhL = (const float*)d_in[9];
  const float* Wfc = (const float*)d_in[10];
  const float* bfc = (const float*)d_in[11];
  float* out = (float*)d_out;
  float* hn = out + (size_t)M_ * O_;

  char* ws = (char*)d_ws;
  unsigned* prog = (unsigned*)ws;
  unsigned short* ring = (unsigned short*)(ws + 65536);
  unsigned short* seqr = (unsigned short*)(ws + 65536 + (1u << 20));
  unsigned short* s3 = (unsigned short*)(ws + 65536 + (1u << 20) + (12u << 20));
  unsigned short* xhi = (unsigned short*)(ws + 65536 + (1u << 20) + (12u << 20) + (64u << 20));
  unsigned short* xlo = xhi + (size_t)B_ * T_ * I_;

  hipMemsetAsync(ws, 0, 65536, stream);  // progress counters
  splitx_k<<<(B_ * T_ * I_) / 1024, 256, 0, stream>>>(x, xhi, xlo);

  hipFuncSetAttribute((const void*)rnn_k, hipFuncAttributeMaxDynamicSharedMemorySize,
                      64 * 1024);
  rnn_k<<<256, 256, 64 * 1024, stream>>>(hidden, Wih0, Whh0, bih0, bhh0,
                                         WihL, WhhL, bihL, bhhL, xhi, xlo,
                                         ring, seqr, s3, hn, prog);

  gemm_k<H_, O_, false, false><<<dim3(O_ / 128, M_ / 128), 256, 48 * 1024, stream>>>(
      (const void*)s3, Wfc, bfc, nullptr, (void*)out);
}